// Round 7
// baseline (263.453 us; speedup 1.0000x reference)
//
#include <hip/hip_runtime.h>
#include <hip/hip_bf16.h>
#include <math.h>

typedef __bf16 bf16x2 __attribute__((ext_vector_type(2)));
typedef __bf16 bf16x4 __attribute__((ext_vector_type(4)));
typedef __bf16 bf16x8 __attribute__((ext_vector_type(8)));
typedef float f32x4 __attribute__((ext_vector_type(4)));
typedef float f32x16 __attribute__((ext_vector_type(16)));

#define MFMA16(a, b, c) __builtin_amdgcn_mfma_f32_16x16x32_bf16(a, b, c, 0, 0, 0)
#define MFMA32(a, b, c) __builtin_amdgcn_mfma_f32_32x32x16_bf16(a, b, c, 0, 0, 0)
#define QSCALE 0.1803368801111204f  // 0.125 * log2(e): folded into W's Q-columns

// async global->LDS, 16B/lane, dest = wave-uniform base + lane*16
__device__ __forceinline__ void gload_lds16(const __bf16* g, __bf16* l) {
  __builtin_amdgcn_global_load_lds((const __attribute__((address_space(1))) void*)g,
                                   (__attribute__((address_space(3))) void*)l,
                                   16, 0, 0);
}

__device__ __forceinline__ bf16x2 shflx32(bf16x2 x) {
  int i;
  __builtin_memcpy(&i, &x, 4);
  i = __shfl_xor(i, 32);
  bf16x2 r;
  __builtin_memcpy(&r, &i, 4);
  return r;
}

// ---------------------------------------------------------------------------
// Kernel 0: convert X fp32 -> bf16
// ---------------------------------------------------------------------------
__global__ __launch_bounds__(256) void convert_x(const float* __restrict__ in,
                                                 __bf16* __restrict__ out) {
  int i = blockIdx.x * 256 + threadIdx.x;
  float4 v = ((const float4*)in)[i];
  bf16x4 o = {(__bf16)v.x, (__bf16)v.y, (__bf16)v.z, (__bf16)v.w};
  *(bf16x4*)&out[i * 4] = o;
}

// ---------------------------------------------------------------------------
// Kernel 1: transpose+convert W fp32 [1024,3072] -> Wt bf16 [3072,1024].
//   Q output-features (bx<16) pre-scaled by 0.125*log2(e).
// ---------------------------------------------------------------------------
__global__ __launch_bounds__(256) void transpose_w(const float* __restrict__ W,
                                                   __bf16* __restrict__ Wt) {
  __shared__ __bf16 tile[64][65];
  const int bx = blockIdx.x;
  const int by = blockIdx.y;
  const int t = threadIdx.x;
  const int lr = t >> 6;
  const int lc = t & 63;
  const float sc = (bx < 16) ? QSCALE : 1.0f;  // block-uniform
#pragma unroll
  for (int i = 0; i < 16; ++i) {
    int r = lr + i * 4;
    tile[r][lc] = (__bf16)(W[(size_t)(by * 64 + r) * 3072 + bx * 64 + lc] * sc);
  }
  __syncthreads();
#pragma unroll
  for (int i = 0; i < 16; ++i) {
    int r = lr + i * 4;
    Wt[(size_t)(bx * 64 + r) * 1024 + by * 64 + lc] = tile[lc][r];
  }
}

// ---------------------------------------------------------------------------
// Kernel 2: QKV = X @ W. 128x128 tile, BK=32, global_load_lds width=16
//   (m97 structure). Unchanged from round 6.
// ---------------------------------------------------------------------------
__global__ __launch_bounds__(256) void gemm_qkv(const __bf16* __restrict__ X,
                                                const __bf16* __restrict__ Wt,
                                                __bf16* __restrict__ QKV) {
  __shared__ __bf16 As[128 * 32];
  __shared__ __bf16 Bs[128 * 32];
  const int t = threadIdx.x;
  const int lane = t & 63;
  const int wave = t >> 6;
  const int quad = lane >> 4;
  const int l16 = lane & 15;
  const int n0 = blockIdx.x * 128;
  const int m0 = blockIdx.y * 128;
  const int wm = (wave & 1) * 64;
  const int wn = (wave >> 1) * 64;

  const __bf16* Ag = &X[(size_t)(m0 + wave * 16 + (lane >> 2)) * 1024 + (lane & 3) * 8];
  const __bf16* Bg = &Wt[(size_t)(n0 + wave * 16 + (lane >> 2)) * 1024 + (lane & 3) * 8];
  __bf16* As0 = &As[wave * 512];
  __bf16* As1 = &As[2048 + wave * 512];
  __bf16* Bs0 = &Bs[wave * 512];
  __bf16* Bs1 = &Bs[2048 + wave * 512];

  f32x4 acc[4][4] = {};

  for (int k0 = 0; k0 < 1024; k0 += 32) {
    gload_lds16(Ag + k0, As0);
    gload_lds16(Ag + (size_t)64 * 1024 + k0, As1);
    gload_lds16(Bg + k0, Bs0);
    gload_lds16(Bg + (size_t)64 * 1024 + k0, Bs1);
    __syncthreads();

    bf16x8 af[4], bf[4];
#pragma unroll
    for (int mi = 0; mi < 4; ++mi)
      af[mi] = *(const bf16x8*)&As[(wm + mi * 16 + l16) * 32 + quad * 8];
#pragma unroll
    for (int ni = 0; ni < 4; ++ni)
      bf[ni] = *(const bf16x8*)&Bs[(wn + ni * 16 + l16) * 32 + quad * 8];
#pragma unroll
    for (int mi = 0; mi < 4; ++mi)
#pragma unroll
      for (int ni = 0; ni < 4; ++ni)
        acc[mi][ni] = MFMA16(af[mi], bf[ni], acc[mi][ni]);
    __syncthreads();
  }

#pragma unroll
  for (int mi = 0; mi < 4; ++mi)
#pragma unroll
    for (int ni = 0; ni < 4; ++ni)
#pragma unroll
      for (int r = 0; r < 4; ++r) {
        int row = m0 + wm + mi * 16 + quad * 4 + r;
        int col = n0 + wn + ni * 16 + l16;
        QKV[(size_t)row * 3072 + col] = (__bf16)acc[mi][ni][r];
      }
}

// ---------------------------------------------------------------------------
// Kernel 3: transpose V part of QKV -> Vt [b*16+h][d=64][key=2048]  bf16
// ---------------------------------------------------------------------------
__global__ __launch_bounds__(256) void transpose_v(const __bf16* __restrict__ QKV,
                                                   __bf16* __restrict__ Vt) {
  __shared__ __bf16 tile[64][65];
  const int k0 = blockIdx.x * 64;
  const int h = blockIdx.y;
  const int b = blockIdx.z;
  const int t = threadIdx.x;
  const int lr = t >> 6;
  const int lc = t & 63;
  const __bf16* src = QKV + (size_t)b * 2048 * 3072 + 2048 + h * 64;
  __bf16* dst = Vt + (size_t)(b * 16 + h) * 64 * 2048;
#pragma unroll
  for (int i = 0; i < 16; ++i) {
    int r = lr + i * 4;
    tile[r][lc] = src[(size_t)(k0 + r) * 3072 + lc];
  }
  __syncthreads();
#pragma unroll
  for (int i = 0; i < 16; ++i) {
    int d = lr + i * 4;
    dst[(size_t)d * 2048 + k0 + lc] = tile[lc][d];
  }
}

// ---------------------------------------------------------------------------
// Kernel 4: flash attention on 32x32x16 MFMA.
//   Wave = 32 q-rows (block 128q, 4 waves). Per 64-key kv-tile:
//   S^T = K.Q^T  (A=K[key][d], B=Q^T; C: col=lane&31=q, row=regmap key
//   [m74/m101-verified map]) -> exp2 -> packed bf16 pairs in regs ->
//   half-swap shfl_xor(32) builds P A-frags (NO Ps LDS round-trip) ->
//   O += P.V with B-frags from Vs[d][key]. Fixed-max softmax as before.
// ---------------------------------------------------------------------------
#define AT_LD 72  // 144B rows, 16B-aligned

__global__ __launch_bounds__(256) void attn(const __bf16* __restrict__ QKV,
                                            const __bf16* __restrict__ Vt,
                                            float* __restrict__ Out) {
  const int h = blockIdx.y;
  const int b = blockIdx.z;
  const int t = threadIdx.x;
  const int lane = t & 63;
  const int wave = t >> 6;
  const int l31 = lane & 31;
  const int half = lane >> 5;
  const int q0w = blockIdx.x * 128 + wave * 32;

  const size_t base = (size_t)b * 2048 * 3072;
  const __bf16* Qb = QKV + base + h * 64;
  const __bf16* Kb = QKV + base + 1024 + h * 64;
  const __bf16* Vtb = Vt + (size_t)(b * 16 + h) * 64 * 2048;  // [d][key]

  __shared__ __bf16 Ks[64 * AT_LD];  // [key][d]
  __shared__ __bf16 Vs[64 * AT_LD];  // [d][key]

  // Q as B-operand: lane holds Q[q0w+l31][dc*16 + half*8 + j]  (pre-scaled)
  bf16x8 qf[4];
#pragma unroll
  for (int dc = 0; dc < 4; ++dc)
    qf[dc] = *(const bf16x8*)&Qb[(size_t)(q0w + l31) * 3072 + dc * 16 + half * 8];

  f32x16 o[2] = {};
  float lsum = 0.0f;

  const int srow = t >> 2;      // staging row 0..63
  const int sc = (t & 3) * 16;  // staging col chunk

  for (int kv0 = 0; kv0 < 2048; kv0 += 64) {
    // ---- stage K [key][d] and V [d][key] ----
    bf16x8 k0v = *(const bf16x8*)&Kb[(size_t)(kv0 + srow) * 3072 + sc];
    bf16x8 k1v = *(const bf16x8*)&Kb[(size_t)(kv0 + srow) * 3072 + sc + 8];
    bf16x8 v0v = *(const bf16x8*)&Vtb[(size_t)srow * 2048 + kv0 + sc];
    bf16x8 v1v = *(const bf16x8*)&Vtb[(size_t)srow * 2048 + kv0 + sc + 8];
    __syncthreads();
    *(bf16x8*)&Ks[srow * AT_LD + sc] = k0v;
    *(bf16x8*)&Ks[srow * AT_LD + sc + 8] = k1v;
    *(bf16x8*)&Vs[srow * AT_LD + sc] = v0v;
    *(bf16x8*)&Vs[srow * AT_LD + sc + 8] = v1v;
    __syncthreads();

    // ---- S^T = K.Q^T per 32-key tile kt; exp2 + pack to bf16 pairs ----
    // lane holds (q=l31, key = kt*32 + (r&3)+8*(r>>2)+4*half) for reg r.
    // pp[kt][g][p] = keys {kt*32 + 8g + 4*half + 2p, +1}
    bf16x2 pp[2][4][2];
#pragma unroll
    for (int kt = 0; kt < 2; ++kt) {
      f32x16 c = {};
#pragma unroll
      for (int dc = 0; dc < 4; ++dc) {
        bf16x8 kf = *(const bf16x8*)&Ks[(kt * 32 + l31) * AT_LD + dc * 16 + half * 8];
        c = MFMA32(kf, qf[dc], c);
      }
#pragma unroll
      for (int g = 0; g < 4; ++g)
#pragma unroll
        for (int p = 0; p < 2; ++p) {
          float e0 = __builtin_amdgcn_exp2f(c[g * 4 + p * 2]);
          float e1 = __builtin_amdgcn_exp2f(c[g * 4 + p * 2 + 1]);
          lsum += e0 + e1;
          pp[kt][g][p] = bf16x2{(__bf16)e0, (__bf16)e1};
        }
    }

    // ---- P A-frags via half-swap; PV ----
    // Target A-frag kk: lane needs keys kk*16 + half*8 + j (j=0..7):
    //   dwords j2=0,1 from half 0, j2=2,3 from half 1, group g=(2kk+half)&3.
    bf16x8 pf[4];
#pragma unroll
    for (int kk = 0; kk < 4; ++kk) {
      const int kt = kk >> 1;
      const int g0 = (2 * kk) & 3;
      const int g1 = (2 * kk + 1) & 3;
      bf16x2 x0 = pp[kt][g0][0], x1 = pp[kt][g0][1];
      bf16x2 y0 = pp[kt][g1][0], y1 = pp[kt][g1][1];
      bf16x2 a0 = half ? y0 : x0;  // my-g values (local-correct half)
      bf16x2 a1 = half ? y1 : x1;
      bf16x2 r0 = shflx32(half ? x0 : y0);  // partner's value at my g
      bf16x2 r1 = shflx32(half ? x1 : y1);
      union { bf16x8 v; bf16x2 hh[4]; } f;
      f.hh[0] = half ? r0 : a0;  // keys kk*16 + half*8 + {0,1}
      f.hh[1] = half ? r1 : a1;  //                      {2,3}
      f.hh[2] = half ? a0 : r0;  //                      {4,5}
      f.hh[3] = half ? a1 : r1;  //                      {6,7}
      pf[kk] = f.v;
    }

#pragma unroll
    for (int dt = 0; dt < 2; ++dt)
#pragma unroll
      for (int kk = 0; kk < 4; ++kk) {
        bf16x8 vf = *(const bf16x8*)&Vs[(dt * 32 + l31) * AT_LD + kk * 16 + half * 8];
        o[dt] = MFMA32(pf[kk], vf, o[dt]);
      }
  }

  // ---- denominator: the two halves partition each q's keys ----
  lsum += __shfl_xor(lsum, 32);
  float inv = 1.0f / lsum;  // valid at lane with l31 == q

  float iv[16];
#pragma unroll
  for (int r = 0; r < 16; ++r)
    iv[r] = __shfl(inv, (r & 3) + 8 * (r >> 2) + 4 * half);

  // ---- epilogue: O C-layout col=l31=d(+32dt), row=q regmap ----
#pragma unroll
  for (int dt = 0; dt < 2; ++dt)
#pragma unroll
    for (int r = 0; r < 16; ++r) {
      int qr = (r & 3) + 8 * (r >> 2) + 4 * half;
      Out[(size_t)(b * 2048 + q0w + qr) * 1024 + h * 64 + dt * 32 + l31] =
          o[dt][r] * iv[r];
    }
}

// ---------------------------------------------------------------------------
extern "C" void kernel_launch(void* const* d_in, const int* in_sizes, int n_in,
                              void* d_out, int out_size, void* d_ws, size_t ws_size,
                              hipStream_t stream) {
  const float* x = (const float*)d_in[0];        // [4,2048,1024] fp32
  const float* w = (const float*)d_in[1];        // [1024,3072]  fp32
  float* out = (float*)d_out;                    // [4,2048,1024] fp32

  __bf16* Wt = (__bf16*)d_ws;                    // [3072,1024]   6.29 MB
  __bf16* QKV = Wt + (size_t)3072 * 1024;        // [8192,3072]  50.33 MB
  __bf16* Xb = QKV + (size_t)8192 * 3072;        // [8192,1024]  16.78 MB
  __bf16* Vtr = Xb;                              // aliases Xb (dead after GEMM)

  convert_x<<<8192, 256, 0, stream>>>(x, Xb);
  transpose_w<<<dim3(48, 16), 256, 0, stream>>>(w, Wt);
  gemm_qkv<<<dim3(24, 64), 256, 0, stream>>>(Xb, Wt, QKV);
  transpose_v<<<dim3(32, 16, 4), 256, 0, stream>>>(QKV, Vtr);
  attn<<<dim3(16, 16, 4), 256, 0, stream>>>(QKV, Vtr, out);
}

// Round 8
// 234.343 us; speedup vs baseline: 1.1242x; 1.1242x over previous
//
#include <hip/hip_runtime.h>
#include <hip/hip_bf16.h>
#include <math.h>

typedef __bf16 bf16x2 __attribute__((ext_vector_type(2)));
typedef __bf16 bf16x4 __attribute__((ext_vector_type(4)));
typedef __bf16 bf16x8 __attribute__((ext_vector_type(8)));
typedef float f32x4 __attribute__((ext_vector_type(4)));
typedef float f32x16 __attribute__((ext_vector_type(16)));

#define MFMA16(a, b, c) __builtin_amdgcn_mfma_f32_16x16x32_bf16(a, b, c, 0, 0, 0)
#define MFMA32(a, b, c) __builtin_amdgcn_mfma_f32_32x32x16_bf16(a, b, c, 0, 0, 0)
#define QSCALE 0.1803368801111204f  // 0.125 * log2(e): folded into W's Q-columns

// async global->LDS, 16B/lane, dest = wave-uniform base + lane*16
__device__ __forceinline__ void gload_lds16(const __bf16* g, __bf16* l) {
  __builtin_amdgcn_global_load_lds((const __attribute__((address_space(1))) void*)g,
                                   (__attribute__((address_space(3))) void*)l,
                                   16, 0, 0);
}

// ---------------------------------------------------------------------------
// Kernel 0: convert X fp32 -> bf16
// ---------------------------------------------------------------------------
__global__ __launch_bounds__(256) void convert_x(const float* __restrict__ in,
                                                 __bf16* __restrict__ out) {
  int i = blockIdx.x * 256 + threadIdx.x;
  float4 v = ((const float4*)in)[i];
  bf16x4 o = {(__bf16)v.x, (__bf16)v.y, (__bf16)v.z, (__bf16)v.w};
  *(bf16x4*)&out[i * 4] = o;
}

// ---------------------------------------------------------------------------
// Kernel 1: transpose+convert W fp32 [1024,3072] -> Wt bf16 [3072,1024].
//   Q output-features (bx<16) pre-scaled by 0.125*log2(e).
// ---------------------------------------------------------------------------
__global__ __launch_bounds__(256) void transpose_w(const float* __restrict__ W,
                                                   __bf16* __restrict__ Wt) {
  __shared__ __bf16 tile[64][65];
  const int bx = blockIdx.x;
  const int by = blockIdx.y;
  const int t = threadIdx.x;
  const int lr = t >> 6;
  const int lc = t & 63;
  const float sc = (bx < 16) ? QSCALE : 1.0f;  // block-uniform
#pragma unroll
  for (int i = 0; i < 16; ++i) {
    int r = lr + i * 4;
    tile[r][lc] = (__bf16)(W[(size_t)(by * 64 + r) * 3072 + bx * 64 + lc] * sc);
  }
  __syncthreads();
#pragma unroll
  for (int i = 0; i < 16; ++i) {
    int r = lr + i * 4;
    Wt[(size_t)(bx * 64 + r) * 1024 + by * 64 + lc] = tile[lc][r];
  }
}

// ---------------------------------------------------------------------------
// Kernel 2: QKV = X @ W. 128x128 tile, BK=32, global_load_lds width=16.
//   Q,K columns (n<2048) -> QK [8192,2048] row-major.
//   V columns (n>=2048)  -> Vt [b*16+h][d=64][key=2048] directly (fused
//   transpose: C-layout gives 4 consecutive keys per reg -> bf16x4 stores).
// ---------------------------------------------------------------------------
__global__ __launch_bounds__(256) void gemm_qkv(const __bf16* __restrict__ X,
                                                const __bf16* __restrict__ Wt,
                                                __bf16* __restrict__ QK,
                                                __bf16* __restrict__ Vt) {
  __shared__ __bf16 As[128 * 32];
  __shared__ __bf16 Bs[128 * 32];
  const int t = threadIdx.x;
  const int lane = t & 63;
  const int wave = t >> 6;
  const int quad = lane >> 4;
  const int l16 = lane & 15;
  const int n0 = blockIdx.x * 128;
  const int m0 = blockIdx.y * 128;
  const int wm = (wave & 1) * 64;
  const int wn = (wave >> 1) * 64;

  const __bf16* Ag = &X[(size_t)(m0 + wave * 16 + (lane >> 2)) * 1024 + (lane & 3) * 8];
  const __bf16* Bg = &Wt[(size_t)(n0 + wave * 16 + (lane >> 2)) * 1024 + (lane & 3) * 8];
  __bf16* As0 = &As[wave * 512];
  __bf16* As1 = &As[2048 + wave * 512];
  __bf16* Bs0 = &Bs[wave * 512];
  __bf16* Bs1 = &Bs[2048 + wave * 512];

  f32x4 acc[4][4] = {};

  for (int k0 = 0; k0 < 1024; k0 += 32) {
    gload_lds16(Ag + k0, As0);
    gload_lds16(Ag + (size_t)64 * 1024 + k0, As1);
    gload_lds16(Bg + k0, Bs0);
    gload_lds16(Bg + (size_t)64 * 1024 + k0, Bs1);
    __syncthreads();

    bf16x8 af[4], bf[4];
#pragma unroll
    for (int mi = 0; mi < 4; ++mi)
      af[mi] = *(const bf16x8*)&As[(wm + mi * 16 + l16) * 32 + quad * 8];
#pragma unroll
    for (int ni = 0; ni < 4; ++ni)
      bf[ni] = *(const bf16x8*)&Bs[(wn + ni * 16 + l16) * 32 + quad * 8];
#pragma unroll
    for (int mi = 0; mi < 4; ++mi)
#pragma unroll
      for (int ni = 0; ni < 4; ++ni)
        acc[mi][ni] = MFMA16(af[mi], bf[ni], acc[mi][ni]);
    __syncthreads();
  }

  if (n0 < 2048) {
    // Q/K epilogue: row-major QK, stride 2048
#pragma unroll
    for (int mi = 0; mi < 4; ++mi)
#pragma unroll
      for (int ni = 0; ni < 4; ++ni)
#pragma unroll
        for (int r = 0; r < 4; ++r) {
          int row = m0 + wm + mi * 16 + quad * 4 + r;
          int col = n0 + wn + ni * 16 + l16;
          QK[(size_t)row * 2048 + col] = (__bf16)acc[mi][ni][r];
        }
  } else {
    // V epilogue: fused transpose into Vt[bh][d][key]; 4 consecutive keys
#pragma unroll
    for (int mi = 0; mi < 4; ++mi)
#pragma unroll
      for (int ni = 0; ni < 4; ++ni) {
        int v = n0 + wn + ni * 16 + l16 - 2048;
        int hh = v >> 6, d = v & 63;
        int row0 = m0 + wm + mi * 16 + quad * 4;
        int bb = row0 >> 11, key = row0 & 2047;
        bf16x4 pk = {(__bf16)acc[mi][ni][0], (__bf16)acc[mi][ni][1],
                     (__bf16)acc[mi][ni][2], (__bf16)acc[mi][ni][3]};
        *(bf16x4*)&Vt[((size_t)(bb * 16 + hh) * 64 + d) * 2048 + key] = pk;
      }
  }
}

// ---------------------------------------------------------------------------
// Kernel 3: flash attention, 32x32x16 MFMA, PERMUTED-K staging.
//   K is staged with LDS row = swap23(src row) (bits 2<->3). With that
//   permutation, S^T's C-layout (col=q, row=(r&3)+8*(r>>2)+4*half) lands each
//   lane's exp2 outputs EXACTLY in PV A-operand order:
//     pf[2*kt+kkl][j] = exp2(c_kt[8*kkl + 4*(j>>2) + (j&3)])
//   -> no LDS round-trip, no shuffles, no selects for P. Fixed-max softmax;
//   denominator = per-lane sum (+ one shfl_xor(32): halves partition keys).
// ---------------------------------------------------------------------------
#define AT_LD 72  // 144B rows, 16B-aligned

__global__ __launch_bounds__(256) void attn(const __bf16* __restrict__ QK,
                                            const __bf16* __restrict__ Vt,
                                            float* __restrict__ Out) {
  const int h = blockIdx.y;
  const int b = blockIdx.z;
  const int t = threadIdx.x;
  const int lane = t & 63;
  const int wave = t >> 6;
  const int l31 = lane & 31;
  const int half = lane >> 5;
  const int q0w = blockIdx.x * 128 + wave * 32;

  const size_t base = (size_t)b * 2048 * 2048;
  const __bf16* Qb = QK + base + h * 64;
  const __bf16* Kb = QK + base + 1024 + h * 64;
  const __bf16* Vtb = Vt + (size_t)(b * 16 + h) * 64 * 2048;  // [d][key]

  __shared__ __bf16 Ks[64 * AT_LD];  // [perm(key)][d]
  __shared__ __bf16 Vs[64 * AT_LD];  // [d][key]

  // Q as B-operand: lane holds Q[q0w+l31][dc*16 + half*8 + j]  (pre-scaled)
  bf16x8 qf[4];
#pragma unroll
  for (int dc = 0; dc < 4; ++dc)
    qf[dc] = *(const bf16x8*)&Qb[(size_t)(q0w + l31) * 2048 + dc * 16 + half * 8];

  f32x16 o[2] = {};
  float lsum = 0.0f;

  const int srow = t >> 2;      // staging row 0..63
  const int sc = (t & 3) * 16;  // staging col chunk
  // K dest row: swap bits 2<->3 (involution); bits 0,1,4,5 kept
  const int prow = (srow & 51) | ((srow & 4) << 1) | ((srow & 8) >> 1);

  for (int kv0 = 0; kv0 < 2048; kv0 += 64) {
    // ---- stage K (row-permuted) and V ----
    bf16x8 k0v = *(const bf16x8*)&Kb[(size_t)(kv0 + srow) * 2048 + sc];
    bf16x8 k1v = *(const bf16x8*)&Kb[(size_t)(kv0 + srow) * 2048 + sc + 8];
    bf16x8 v0v = *(const bf16x8*)&Vtb[(size_t)srow * 2048 + kv0 + sc];
    bf16x8 v1v = *(const bf16x8*)&Vtb[(size_t)srow * 2048 + kv0 + sc + 8];
    __syncthreads();
    *(bf16x8*)&Ks[prow * AT_LD + sc] = k0v;
    *(bf16x8*)&Ks[prow * AT_LD + sc + 8] = k1v;
    *(bf16x8*)&Vs[srow * AT_LD + sc] = v0v;
    *(bf16x8*)&Vs[srow * AT_LD + sc + 8] = v1v;
    __syncthreads();

    // ---- S^T = K.Q^T per 32-row tile; exp2 directly into A-frag order ----
    bf16x8 pf[4];
#pragma unroll
    for (int kt = 0; kt < 2; ++kt) {
      f32x16 c = {};
#pragma unroll
      for (int dc = 0; dc < 4; ++dc) {
        bf16x8 kf = *(const bf16x8*)&Ks[(kt * 32 + l31) * AT_LD + dc * 16 + half * 8];
        c = MFMA32(kf, qf[dc], c);
      }
#pragma unroll
      for (int kkl = 0; kkl < 2; ++kkl) {
        bf16x8 f;
#pragma unroll
        for (int j = 0; j < 8; ++j) {
          float e = __builtin_amdgcn_exp2f(c[8 * kkl + 4 * (j >> 2) + (j & 3)]);
          lsum += e;
          f[j] = (__bf16)e;
        }
        pf[kt * 2 + kkl] = f;
      }
    }

    // ---- O += P V ----
#pragma unroll
    for (int dt = 0; dt < 2; ++dt)
#pragma unroll
      for (int kk = 0; kk < 4; ++kk) {
        bf16x8 vf = *(const bf16x8*)&Vs[(dt * 32 + l31) * AT_LD + kk * 16 + half * 8];
        o[dt] = MFMA32(pf[kk], vf, o[dt]);
      }
  }

  // ---- denominator: the two halves partition each q's keys ----
  lsum += __shfl_xor(lsum, 32);
  float inv = 1.0f / lsum;  // valid for q == l31

  float iv[16];
#pragma unroll
  for (int r = 0; r < 16; ++r)
    iv[r] = __shfl(inv, (r & 3) + 8 * (r >> 2) + 4 * half);

  // ---- epilogue: O C-layout col=l31=d(+32dt), row=q regmap ----
#pragma unroll
  for (int dt = 0; dt < 2; ++dt)
#pragma unroll
    for (int r = 0; r < 16; ++r) {
      int qr = (r & 3) + 8 * (r >> 2) + 4 * half;
      Out[(size_t)(b * 2048 + q0w + qr) * 1024 + h * 64 + dt * 32 + l31] =
          o[dt][r] * iv[r];
    }
}

// ---------------------------------------------------------------------------
extern "C" void kernel_launch(void* const* d_in, const int* in_sizes, int n_in,
                              void* d_out, int out_size, void* d_ws, size_t ws_size,
                              hipStream_t stream) {
  const float* x = (const float*)d_in[0];        // [4,2048,1024] fp32
  const float* w = (const float*)d_in[1];        // [1024,3072]  fp32
  float* out = (float*)d_out;                    // [4,2048,1024] fp32

  __bf16* Wt = (__bf16*)d_ws;                    // [3072,1024]   6.29 MB
  __bf16* QK = Wt + (size_t)3072 * 1024;         // [8192,2048]  33.55 MB
  __bf16* Xb = QK + (size_t)8192 * 2048;         // [8192,1024]  16.78 MB
  __bf16* Vtr = Xb + (size_t)8192 * 1024;        // [64,64,2048] 16.78 MB

  convert_x<<<8192, 256, 0, stream>>>(x, Xb);
  transpose_w<<<dim3(48, 16), 256, 0, stream>>>(w, Wt);
  gemm_qkv<<<dim3(24, 64), 256, 0, stream>>>(Xb, Wt, QK, Vtr);
  attn<<<dim3(16, 16, 4), 256, 0, stream>>>(QK, Vtr, out);
}